// Round 1
// baseline (393.857 us; speedup 1.0000x reference)
//
#include <hip/hip_runtime.h>
#include <cstdint>

#define AS1 __attribute__((address_space(1)))
#define AS3 __attribute__((address_space(3)))

typedef __attribute__((ext_vector_type(8))) __bf16 bf16x8;
typedef __attribute__((ext_vector_type(16))) float f32x16;

static constexpr int SPLIT = 8, BM = 256, BN = 64;
static constexpr int KPS = 8192 / SPLIT;   // 1024 keys per split
static constexpr int ITERS = KPS / BN;     // 16

// workspace layout (bytes); total = 76.25 MB
static constexpr size_t OFF_QB = 0;               // bf16 [8192][256] (pre-scaled by 1/16)
static constexpr size_t OFF_KB = 4ull << 20;      // bf16 [8192][256]
static constexpr size_t OFF_VT = 8ull << 20;      // bf16 [256][8192] (V transposed)
static constexpr size_t OFF_OP = 12ull << 20;     // f32  [8][8192][256] per-split normalized O
static constexpr size_t OFF_ME = 76ull << 20;     // f32  [8][8192]     m + log(l)

__device__ __forceinline__ unsigned short f2bf(float f) {
  uint32_t b = __builtin_bit_cast(uint32_t, f);
  b += 0x7fffu + ((b >> 16) & 1u);   // RNE, inputs are finite normals
  return (unsigned short)(b >> 16);
}

// ---- prep: fp32 -> bf16 for Q (x 1/16) and K --------------------------------
__global__ __launch_bounds__(256) void cvt_qk(const float* __restrict__ q,
                                              const float* __restrict__ k,
                                              unsigned short* __restrict__ qb,
                                              unsigned short* __restrict__ kb) {
  int i = blockIdx.x * 256 + threadIdx.x;          // float4 index, 0..1048575
  const bool isQ = i < 524288;
  const float sc = isQ ? 0.0625f : 1.0f;
  const float4 v = isQ ? ((const float4*)q)[i] : ((const float4*)k)[i - 524288];
  ushort4 u;
  u.x = f2bf(v.x * sc); u.y = f2bf(v.y * sc);
  u.z = f2bf(v.z * sc); u.w = f2bf(v.w * sc);
  if (isQ) ((ushort4*)qb)[i] = u; else ((ushort4*)kb)[i - 524288] = u;
}

// ---- prep: V [8192][256] f32  ->  Vt [256][8192] bf16 -----------------------
__global__ __launch_bounds__(256) void tr_v(const float* __restrict__ v,
                                            unsigned short* __restrict__ vt) {
  __shared__ float tile[64][65];
  const int m0 = blockIdx.x * 64, d0 = blockIdx.y * 64;
  const int r = threadIdx.x >> 6, c = threadIdx.x & 63;
#pragma unroll
  for (int i = 0; i < 16; ++i)
    tile[r + 4 * i][c] = v[(size_t)(m0 + r + 4 * i) * 256 + d0 + c];
  __syncthreads();
#pragma unroll
  for (int i = 0; i < 16; ++i)
    vt[(size_t)(d0 + r + 4 * i) * 8192 + m0 + c] = f2bf(tile[c][r + 4 * i]);
}

// ---- main flash-attention kernel --------------------------------------------
// grid 256 = 32 q-blocks x 8 splits (split = bid&7 -> XCD-affine), 512 threads.
// LDS: Kt 32KB | Vt 32KB | S/P 64KB (overlay) | m/l/alpha 3KB  = 134144 B
__global__ __launch_bounds__(512) void attn(const unsigned short* __restrict__ qbm,
                                            const unsigned short* __restrict__ kbm,
                                            const unsigned short* __restrict__ vtm,
                                            float* __restrict__ opart,
                                            float* __restrict__ meff) {
  extern __shared__ char smem[];
  char* Kt = smem;                 // 64 keys x 512B, chunk c stored at c^(row&7)
  char* Vt = smem + 32768;         // 256 dv x 128B, chunk c stored at c^(dv&7)
  char* SP = smem + 65536;         // 256 q x 256B (S f32 / P bf16 overlay), swizzled
  float* m_l = (float*)(smem + 131072);
  float* l_l = (float*)(smem + 131072 + 1024);
  float* a_l = (float*)(smem + 131072 + 2048);

  const int tid = threadIdx.x;
  const int w = tid >> 6, lane = tid & 63;
  const int ml = lane & 31, h = lane >> 5;
  const int bid = blockIdx.x;
  const int split = bid & 7, qblk = bid >> 3;
  const int q0 = qblk * BM;

  AS3 char* sm3 = (AS3 char*)smem;

  if (tid < 256) { m_l[tid] = -1e30f; l_l[tid] = 0.f; }

  // Q fragments in registers: wave w owns queries q0 + w*32 .. +31 (all 256 d)
  bf16x8 qf[16];
  {
    const char* qrow = (const char*)qbm + (size_t)(q0 + w * 32 + ml) * 512 + h * 16;
#pragma unroll
    for (int s = 0; s < 16; ++s)
      qf[s] = __builtin_bit_cast(bf16x8, *(const uint4*)(qrow + s * 32));
  }

  f32x16 oa[8];
#pragma unroll
  for (int d = 0; d < 8; ++d)
#pragma unroll
    for (int r = 0; r < 16; ++r) oa[d][r] = 0.f;

  for (int it = 0; it < ITERS; ++it) {
    const int kb = split * KPS + it * BN;
    __syncthreads();                                     // prev PV done with Kt/Vt/P
    // stage K tile: 2048 x 16B chunks, global-side XOR swizzle
#pragma unroll
    for (int i = 0; i < 4; ++i) {
      int slot = i * 512 + w * 64 + lane;
      int row = slot >> 5, cs = slot & 31;
      int c = (cs & 24) | ((cs ^ row) & 7);
      const AS1 char* g = (const AS1 char*)kbm + (size_t)(kb + row) * 512 + c * 16;
      __builtin_amdgcn_global_load_lds((const AS1 uint32_t*)g,
          (AS3 uint32_t*)(sm3 + (i * 512 + w * 64) * 16), 16, 0, 0);
    }
    // stage Vt tile: 2048 x 16B chunks
#pragma unroll
    for (int i = 0; i < 4; ++i) {
      int slot = i * 512 + w * 64 + lane;
      int dv = slot >> 3, cs = slot & 7;
      int c = cs ^ (dv & 7);
      const AS1 char* g = (const AS1 char*)vtm + (size_t)dv * 16384 + kb * 2 + c * 16;
      __builtin_amdgcn_global_load_lds((const AS1 uint32_t*)g,
          (AS3 uint32_t*)(sm3 + 32768 + (i * 512 + w * 64) * 16), 16, 0, 0);
    }
    __syncthreads();                                     // staged (drains vmcnt)

    // ---- QK^T: S(32q x 64k) per wave, A = Q regs, B = K LDS ----
    f32x16 sa[2];
#pragma unroll
    for (int kt = 0; kt < 2; ++kt)
#pragma unroll
      for (int r = 0; r < 16; ++r) sa[kt][r] = 0.f;
    {
      const char* kr0 = Kt + (size_t)ml * 512;
      const char* kr1 = Kt + (size_t)(ml + 32) * 512;
      const int x0 = ml & 7;                 // (ml+32)&7 == ml&7
#pragma unroll
      for (int s = 0; s < 16; ++s) {
        int cx = ((2 * s + h) ^ x0) << 4;
        bf16x8 b0 = __builtin_bit_cast(bf16x8, *(const uint4*)(kr0 + cx));
        bf16x8 b1 = __builtin_bit_cast(bf16x8, *(const uint4*)(kr1 + cx));
        sa[0] = __builtin_amdgcn_mfma_f32_32x32x16_bf16(qf[s], b0, sa[0], 0, 0, 0);
        sa[1] = __builtin_amdgcn_mfma_f32_32x32x16_bf16(qf[s], b1, sa[1], 0, 0, 0);
      }
    }
    // write S (f32, swizzled): C layout col=lane&31, row=(r&3)+8*(r>>2)+4*h
#pragma unroll
    for (int r = 0; r < 16; ++r) {
      int qrow = w * 32 + (r & 3) + 8 * (r >> 2) + 4 * h;
      char* srow = SP + qrow * 256;
      int q7 = qrow & 7;
#pragma unroll
      for (int kt = 0; kt < 2; ++kt) {
        int key = kt * 32 + ml;
        *(float*)(srow + (((key >> 2) ^ q7) << 4) + (key & 3) * 4) = sa[kt][r];
      }
    }
    __syncthreads();

    // ---- online softmax: 2 threads per row, 32 keys each ----
    const int row = tid >> 1, half = tid & 1;
    const int r7 = row & 7;
    float sv[32];
    {
      const char* srow = SP + row * 256;
#pragma unroll
      for (int i = 0; i < 8; ++i) {
        float4 f = *(const float4*)(srow + (((8 * half + i) ^ r7) << 4));
        sv[4 * i] = f.x; sv[4 * i + 1] = f.y; sv[4 * i + 2] = f.z; sv[4 * i + 3] = f.w;
      }
    }
    float mx = -1e30f;
#pragma unroll
    for (int j = 0; j < 32; ++j) mx = fmaxf(mx, sv[j]);
    mx = fmaxf(mx, __shfl_xor(mx, 1));
    float mold = m_l[row];
    float mnew = fmaxf(mold, mx);
    float alpha = __expf(mold - mnew);
    float ls = 0.f;
#pragma unroll
    for (int j = 0; j < 32; ++j) { sv[j] = __expf(sv[j] - mnew); ls += sv[j]; }
    ls += __shfl_xor(ls, 1);
    if (!half) { m_l[row] = mnew; l_l[row] = l_l[row] * alpha + ls; a_l[row] = alpha; }
    __syncthreads();                                     // all S reads done
    // write P (bf16) over the S buffer, swizzled
    {
      char* srow = SP + row * 256;
#pragma unroll
      for (int i = 0; i < 4; ++i) {
        uint32_t p0 = f2bf(sv[8 * i + 0]) | ((uint32_t)f2bf(sv[8 * i + 1]) << 16);
        uint32_t p1 = f2bf(sv[8 * i + 2]) | ((uint32_t)f2bf(sv[8 * i + 3]) << 16);
        uint32_t p2 = f2bf(sv[8 * i + 4]) | ((uint32_t)f2bf(sv[8 * i + 5]) << 16);
        uint32_t p3 = f2bf(sv[8 * i + 6]) | ((uint32_t)f2bf(sv[8 * i + 7]) << 16);
        *(uint4*)(srow + (((4 * half + i) ^ r7) << 4)) = make_uint4(p0, p1, p2, p3);
      }
    }
    __syncthreads();                                     // P ready

    // ---- rescale O by alpha, then PV: O(32q x 256dv) += P x V ----
#pragma unroll
    for (int r = 0; r < 16; ++r) {
      float a = a_l[w * 32 + (r & 3) + 8 * (r >> 2) + 4 * h];
#pragma unroll
      for (int d = 0; d < 8; ++d) oa[d][r] *= a;
    }
    {
      const int qrow = w * 32 + ml;
      const char* prow = SP + qrow * 256;
      const int q7 = qrow & 7, v7 = ml & 7;
#pragma unroll
      for (int s4 = 0; s4 < 4; ++s4) {
        int c = 2 * s4 + h;
        bf16x8 pa = __builtin_bit_cast(bf16x8, *(const uint4*)(prow + ((c ^ q7) << 4)));
#pragma unroll
        for (int d = 0; d < 8; ++d) {
          const char* vrow = Vt + (size_t)(d * 32 + ml) * 128;
          bf16x8 vb = __builtin_bit_cast(bf16x8, *(const uint4*)(vrow + ((c ^ v7) << 4)));
          oa[d] = __builtin_amdgcn_mfma_f32_32x32x16_bf16(pa, vb, oa[d], 0, 0, 0);
        }
      }
    }
  }
  __syncthreads();

  // epilogue: per-split normalized O + m_eff
#pragma unroll
  for (int r = 0; r < 16; ++r) {
    int qrow = w * 32 + (r & 3) + 8 * (r >> 2) + 4 * h;
    float inv = 1.f / l_l[qrow];
    size_t base = ((size_t)split * 8192 + q0 + qrow) * 256;
#pragma unroll
    for (int d = 0; d < 8; ++d)
      opart[base + d * 32 + ml] = oa[d][r] * inv;
  }
  if (tid < 256)
    meff[split * 8192 + q0 + tid] = m_l[tid] + __logf(l_l[tid]);
}

// ---- combine: log-sum-exp merge of the 8 splits -----------------------------
__global__ __launch_bounds__(256) void combine(const float* __restrict__ opart,
                                               const float* __restrict__ meff,
                                               float* __restrict__ out) {
  const int r = blockIdx.x, t = threadIdx.x;
  float me[8], M = -1e30f;
#pragma unroll
  for (int s = 0; s < 8; ++s) { me[s] = meff[s * 8192 + r]; M = fmaxf(M, me[s]); }
  float wsum = 0.f, acc = 0.f;
#pragma unroll
  for (int s = 0; s < 8; ++s) {
    float wgt = __expf(me[s] - M);
    wsum += wgt;
    acc += wgt * opart[((size_t)s * 8192 + r) * 256 + t];
  }
  out[(size_t)r * 256 + t] = acc / wsum;
}

extern "C" void kernel_launch(void* const* d_in, const int* in_sizes, int n_in,
                              void* d_out, int out_size, void* d_ws, size_t ws_size,
                              hipStream_t stream) {
  const float* q = (const float*)d_in[0];
  const float* k = (const float*)d_in[1];
  const float* v = (const float*)d_in[2];
  char* ws = (char*)d_ws;
  unsigned short* qb = (unsigned short*)(ws + OFF_QB);
  unsigned short* kb = (unsigned short*)(ws + OFF_KB);
  unsigned short* vt = (unsigned short*)(ws + OFF_VT);
  float* op = (float*)(ws + OFF_OP);
  float* me = (float*)(ws + OFF_ME);
  float* out = (float*)d_out;

  // 134144 B dynamic LDS (> 64 KB default cap); idempotent, safe under capture
  hipFuncSetAttribute((const void*)attn, hipFuncAttributeMaxDynamicSharedMemorySize,
                      134144);

  cvt_qk<<<4096, 256, 0, stream>>>(q, k, qb, kb);
  tr_v<<<dim3(128, 4), 256, 0, stream>>>(v, vt);
  attn<<<256, 512, 134144, stream>>>(qb, kb, vt, op, me);
  combine<<<8192, 256, 0, stream>>>(op, me, out);
}

// Round 2
// 370.233 us; speedup vs baseline: 1.0638x; 1.0638x over previous
//
#include <hip/hip_runtime.h>
#include <cstdint>

typedef __attribute__((ext_vector_type(8))) __bf16 bf16x8;
typedef __attribute__((ext_vector_type(16))) float f32x16;

static constexpr int SPLIT = 4;
static constexpr int BM = 64;              // queries per block
static constexpr int BN = 64;              // keys per iteration
static constexpr int KPS = 8192 / SPLIT;   // 2048 keys per split
static constexpr int ITERS = KPS / BN;     // 32

// workspace layout (bytes); total ~44.2 MB
static constexpr size_t OFF_QB = 0;               // bf16 [8192][256] Q * 1/16
static constexpr size_t OFF_KP = 4ull << 20;      // bf16 packed K frags (4 MB)
static constexpr size_t OFF_VP = 8ull << 20;      // bf16 packed V frags (4 MB)
static constexpr size_t OFF_OP = 12ull << 20;     // f32 [4][8192][256] per-split O
static constexpr size_t OFF_ME = 44ull << 20;     // f32 [4][8192] m + log(l)

__device__ __forceinline__ unsigned short f2bf(float f) {
  uint32_t b = __builtin_bit_cast(uint32_t, f);
  b += 0x7fffu + ((b >> 16) & 1u);   // RNE
  return (unsigned short)(b >> 16);
}

// ---- prep: Q f32 -> bf16 (x 1/16) ------------------------------------------
__global__ __launch_bounds__(256) void cvt_q(const float* __restrict__ q,
                                             unsigned short* __restrict__ qb) {
  int i = blockIdx.x * 256 + threadIdx.x;          // float4 idx, 0..524287
  float4 v = ((const float4*)q)[i];
  ushort4 u;
  u.x = f2bf(v.x * 0.0625f); u.y = f2bf(v.y * 0.0625f);
  u.z = f2bf(v.z * 0.0625f); u.w = f2bf(v.w * 0.0625f);
  ((ushort4*)qb)[i] = u;
}

// ---- prep: K [8192][256] f32 -> Kp fragment order ---------------------------
// Kp chunk (16B) index = (t*8192 + m)*2 + h,  holds K[m][t*16 + h*8 .. +7] bf16
__global__ __launch_bounds__(256) void pack_k(const float* __restrict__ k,
                                              unsigned short* __restrict__ kp) {
  __shared__ unsigned short lds[64 * 264];
  const int m0 = blockIdx.x * 64, tid = threadIdx.x;
  const int c4 = tid & 63;
#pragma unroll
  for (int i = 0; i < 16; ++i) {
    int row = (tid >> 6) + i * 4;
    float4 f = ((const float4*)k)[(size_t)(m0 + row) * 64 + c4];
    uint32_t lo = f2bf(f.x) | ((uint32_t)f2bf(f.y) << 16);
    uint32_t hi = f2bf(f.z) | ((uint32_t)f2bf(f.w) << 16);
    *(uint2*)&lds[row * 264 + c4 * 4] = make_uint2(lo, hi);
  }
  __syncthreads();
  const int m = (tid >> 1) & 63, h = tid & 1, thi = tid >> 7;
#pragma unroll
  for (int tt = 0; tt < 8; ++tt) {
    int t = tt * 2 + thi;
    uint4 v = *(const uint4*)&lds[m * 264 + t * 16 + h * 8];
    ((uint4*)kp)[(size_t)(t * 8192 + m0 + m) * 2 + h] = v;
  }
}

// ---- prep: V [8192][256] f32 -> Vp fragment order ---------------------------
// Vp chunk (16B) index = (t*256 + n)*2 + h, holds V[t*16 + h*8 + j][n] bf16
__global__ __launch_bounds__(256) void pack_v(const float* __restrict__ v,
                                              unsigned short* __restrict__ vp) {
  __shared__ unsigned short lds[16 * 264];
  const int t = blockIdx.x, tid = threadIdx.x;
  const int c4 = tid & 63;
#pragma unroll
  for (int i = 0; i < 4; ++i) {
    int row = (tid >> 6) + i * 4;
    float4 f = ((const float4*)v)[(size_t)(t * 16 + row) * 64 + c4];
    uint32_t lo = f2bf(f.x) | ((uint32_t)f2bf(f.y) << 16);
    uint32_t hi = f2bf(f.z) | ((uint32_t)f2bf(f.w) << 16);
    *(uint2*)&lds[row * 264 + c4 * 4] = make_uint2(lo, hi);
  }
  __syncthreads();
#pragma unroll
  for (int p = 0; p < 2; ++p) {
    int cc = tid + p * 256;
    int n = cc >> 1, h = cc & 1;
    uint32_t w[4];
#pragma unroll
    for (int jj = 0; jj < 4; ++jj) {
      unsigned short a = lds[(h * 8 + 2 * jj) * 264 + n];
      unsigned short b = lds[(h * 8 + 2 * jj + 1) * 264 + n];
      w[jj] = (uint32_t)a | ((uint32_t)b << 16);
    }
    ((uint4*)vp)[(size_t)(t * 256 + n) * 2 + h] = make_uint4(w[0], w[1], w[2], w[3]);
  }
}

// ---- main attention: barrier-free, wave-independent -------------------------
// grid 512 = 128 qblks x 4 splits (split = bid>>7, contiguous-bid chunks).
// block 256 thr = 4 waves: wave (qt = w>>1, dh = w&1) owns 32q x 128dv.
__global__ __launch_bounds__(256, 2) void attn(const unsigned short* __restrict__ qbm,
                                               const unsigned short* __restrict__ kpm,
                                               const unsigned short* __restrict__ vpm,
                                               float* __restrict__ opart,
                                               float* __restrict__ meff) {
  __shared__ char ssc[4][8192];          // per-wave S scratch, XOR-swizzled 16B chunks
  __shared__ float alpha_s[4][32];
  __shared__ float l_s[4][32];

  const int tid = threadIdx.x;
  const int w = tid >> 6, lane = tid & 63;
  const int ml = lane & 31, h = lane >> 5;
  const int qt = w >> 1, dh = w & 1;
  const int bid = blockIdx.x;
  const int split = bid >> 7, qblk = bid & 127;
  const int q0 = qblk * BM;

  const uint4* kp4 = (const uint4*)kpm;
  const uint4* vp4 = (const uint4*)vpm;
  char* sw = ssc[w];

  // Q fragments: wave's 32 q-rows, full D=256
  bf16x8 qf[16];
  {
    const char* qrow = (const char*)qbm + (size_t)(q0 + qt * 32 + ml) * 512 + h * 16;
#pragma unroll
    for (int s = 0; s < 16; ++s)
      qf[s] = __builtin_bit_cast(bf16x8, *(const uint4*)(qrow + s * 32));
  }

  f32x16 oa[4];
#pragma unroll
  for (int nt = 0; nt < 4; ++nt)
#pragma unroll
    for (int r = 0; r < 16; ++r) oa[nt][r] = 0.f;
  float m_run = -1e30f, l_run = 0.f;

  for (int it = 0; it < ITERS; ++it) {
    const int kb = split * KPS + it * BN;
    const int t0 = kb >> 4;

    // ---- QK^T: S(32q x 64k), A = Q regs, B = Kp direct global loads ----
    f32x16 sa0, sa1;
#pragma unroll
    for (int r = 0; r < 16; ++r) { sa0[r] = 0.f; sa1[r] = 0.f; }
#pragma unroll
    for (int s = 0; s < 16; ++s) {
      bf16x8 k0 = __builtin_bit_cast(bf16x8, kp4[(size_t)(s * 8192 + kb + ml) * 2 + h]);
      bf16x8 k1 = __builtin_bit_cast(bf16x8, kp4[(size_t)(s * 8192 + kb + 32 + ml) * 2 + h]);
      sa0 = __builtin_amdgcn_mfma_f32_32x32x16_bf16(qf[s], k0, sa0, 0, 0, 0);
      sa1 = __builtin_amdgcn_mfma_f32_32x32x16_bf16(qf[s], k1, sa1, 0, 0, 0);
    }

    // ---- S -> wave-private LDS (XOR swizzle, conflict-free) ----
#pragma unroll
    for (int r = 0; r < 16; ++r) {
      int row = (r & 3) + 8 * (r >> 2) + 4 * h;
      char* base = sw + row * 256;
      int rx = row & 15;
      {
        int key = ml;            // kt = 0
        *(float*)(base + (((key >> 2) ^ rx) << 4) + (key & 3) * 4) = sa0[r];
      }
      {
        int key = 32 + ml;       // kt = 1
        *(float*)(base + (((key >> 2) ^ rx) << 4) + (key & 3) * 4) = sa1[r];
      }
    }

    // ---- softmax, lane owns q-row = ml, h-half of keys ----
    float vals[32];
    {
      const char* base2 = sw + ml * 256;
      const int rx2 = ml & 15;
#pragma unroll
      for (int s = 0; s < 4; ++s) {
        int c0 = s * 4 + 2 * h;
        float4 a = *(const float4*)(base2 + ((c0 ^ rx2) << 4));
        float4 b = *(const float4*)(base2 + (((c0 + 1) ^ rx2) << 4));
        vals[s * 8 + 0] = a.x; vals[s * 8 + 1] = a.y; vals[s * 8 + 2] = a.z; vals[s * 8 + 3] = a.w;
        vals[s * 8 + 4] = b.x; vals[s * 8 + 5] = b.y; vals[s * 8 + 6] = b.z; vals[s * 8 + 7] = b.w;
      }
    }
    float mx = vals[0];
#pragma unroll
    for (int j = 1; j < 32; ++j) mx = fmaxf(mx, vals[j]);
    mx = fmaxf(mx, __shfl_xor(mx, 32));
    float mnew = fmaxf(m_run, mx);
    float al = __expf(m_run - mnew);
    float ls = 0.f;
#pragma unroll
    for (int j = 0; j < 32; ++j) { vals[j] = __expf(vals[j] - mnew); ls += vals[j]; }
    ls += __shfl_xor(ls, 32);
    l_run = l_run * al + ls;
    m_run = mnew;
    alpha_s[w][ml] = al;                       // both h write same value

    // ---- rescale O by alpha (C-layout rows) ----
#pragma unroll
    for (int r = 0; r < 16; ++r) {
      float a = alpha_s[w][(r & 3) + 8 * (r >> 2) + 4 * h];
#pragma unroll
      for (int nt = 0; nt < 4; ++nt) oa[nt][r] *= a;
    }

    // ---- P fragments (A-layout) straight from regs ----
    bf16x8 pf[4];
#pragma unroll
    for (int s = 0; s < 4; ++s) {
      uint32_t w0 = f2bf(vals[s * 8 + 0]) | ((uint32_t)f2bf(vals[s * 8 + 1]) << 16);
      uint32_t w1 = f2bf(vals[s * 8 + 2]) | ((uint32_t)f2bf(vals[s * 8 + 3]) << 16);
      uint32_t w2 = f2bf(vals[s * 8 + 4]) | ((uint32_t)f2bf(vals[s * 8 + 5]) << 16);
      uint32_t w3 = f2bf(vals[s * 8 + 6]) | ((uint32_t)f2bf(vals[s * 8 + 7]) << 16);
      pf[s] = __builtin_bit_cast(bf16x8, make_uint4(w0, w1, w2, w3));
    }

    // ---- PV: O(32q x 128dv) += P x V, B = Vp direct global loads ----
#pragma unroll
    for (int nt = 0; nt < 4; ++nt) {
#pragma unroll
      for (int s = 0; s < 4; ++s) {
        bf16x8 vb = __builtin_bit_cast(bf16x8,
            vp4[(size_t)((t0 + s) * 256 + dh * 128 + nt * 32 + ml) * 2 + h]);
        oa[nt] = __builtin_amdgcn_mfma_f32_32x32x16_bf16(pf[s], vb, oa[nt], 0, 0, 0);
      }
    }
  }

  // ---- epilogue ----
  l_s[w][ml] = l_run;
#pragma unroll
  for (int r = 0; r < 16; ++r) {
    int row = (r & 3) + 8 * (r >> 2) + 4 * h;
    float inv = 1.f / l_s[w][row];
    size_t base = ((size_t)split * 8192 + q0 + qt * 32 + row) * 256 + dh * 128;
#pragma unroll
    for (int nt = 0; nt < 4; ++nt)
      opart[base + nt * 32 + ml] = oa[nt][r] * inv;
  }
  if (dh == 0 && h == 0)
    meff[split * 8192 + q0 + qt * 32 + ml] = m_run + __logf(l_run);
}

// ---- combine: log-sum-exp merge of the 4 splits -----------------------------
__global__ __launch_bounds__(256) void combine(const float* __restrict__ opart,
                                               const float* __restrict__ meff,
                                               float* __restrict__ out) {
  const int r = blockIdx.x, t = threadIdx.x;
  float me[SPLIT], M = -1e30f;
#pragma unroll
  for (int s = 0; s < SPLIT; ++s) { me[s] = meff[s * 8192 + r]; M = fmaxf(M, me[s]); }
  float wsum = 0.f, acc = 0.f;
#pragma unroll
  for (int s = 0; s < SPLIT; ++s) {
    float wgt = __expf(me[s] - M);
    wsum += wgt;
    acc += wgt * opart[((size_t)s * 8192 + r) * 256 + t];
  }
  out[(size_t)r * 256 + t] = acc / wsum;
}

extern "C" void kernel_launch(void* const* d_in, const int* in_sizes, int n_in,
                              void* d_out, int out_size, void* d_ws, size_t ws_size,
                              hipStream_t stream) {
  const float* q = (const float*)d_in[0];
  const float* k = (const float*)d_in[1];
  const float* v = (const float*)d_in[2];
  char* ws = (char*)d_ws;
  unsigned short* qb = (unsigned short*)(ws + OFF_QB);
  unsigned short* kp = (unsigned short*)(ws + OFF_KP);
  unsigned short* vp = (unsigned short*)(ws + OFF_VP);
  float* op = (float*)(ws + OFF_OP);
  float* me = (float*)(ws + OFF_ME);
  float* out = (float*)d_out;

  cvt_q<<<2048, 256, 0, stream>>>(q, qb);
  pack_k<<<128, 256, 0, stream>>>(k, kp);
  pack_v<<<512, 256, 0, stream>>>(v, vp);
  attn<<<512, 256, 0, stream>>>(qb, kp, vp, op, me);
  combine<<<8192, 256, 0, stream>>>(op, me, out);
}

// Round 3
// 352.127 us; speedup vs baseline: 1.1185x; 1.0514x over previous
//
#include <hip/hip_runtime.h>
#include <cstdint>

#define AS1 __attribute__((address_space(1)))
#define AS3 __attribute__((address_space(3)))

typedef __attribute__((ext_vector_type(8))) __bf16 bf16x8;
typedef __attribute__((ext_vector_type(16))) float f32x16;

static constexpr int SPLIT = 8;
static constexpr int BM = 64;              // queries per block
static constexpr int BN = 64;              // keys per iteration
static constexpr int KPS = 8192 / SPLIT;   // 1024 keys per split
static constexpr int ITERS = KPS / BN;     // 16

// workspace layout (bytes); total ~76.3 MB
static constexpr size_t OFF_QB = 0;               // bf16 [8192][256] Q * 1/16
static constexpr size_t OFF_KP = 4ull << 20;      // bf16 packed K frags (4 MB)
static constexpr size_t OFF_VP = 8ull << 20;      // bf16 packed V frags (4 MB)
static constexpr size_t OFF_OP = 12ull << 20;     // f32 [8][8192][256] per-split O
static constexpr size_t OFF_ME = 76ull << 20;     // f32 [8][8192] m + log(l)

__device__ __forceinline__ unsigned short f2bf(float f) {
  uint32_t b = __builtin_bit_cast(uint32_t, f);
  b += 0x7fffu + ((b >> 16) & 1u);   // RNE
  return (unsigned short)(b >> 16);
}

// ---- prep: Q f32 -> bf16 (x 1/16) ------------------------------------------
__global__ __launch_bounds__(256) void cvt_q(const float* __restrict__ q,
                                             unsigned short* __restrict__ qb) {
  int i = blockIdx.x * 256 + threadIdx.x;          // float4 idx
  float4 v = ((const float4*)q)[i];
  ushort4 u;
  u.x = f2bf(v.x * 0.0625f); u.y = f2bf(v.y * 0.0625f);
  u.z = f2bf(v.z * 0.0625f); u.w = f2bf(v.w * 0.0625f);
  ((ushort4*)qb)[i] = u;
}

// ---- prep: K [8192][256] f32 -> Kp fragment order ---------------------------
// Kp chunk (16B) index = (t*8192 + m)*2 + h,  holds K[m][t*16 + h*8 .. +7] bf16
__global__ __launch_bounds__(256) void pack_k(const float* __restrict__ k,
                                              unsigned short* __restrict__ kp) {
  __shared__ unsigned short lds[64 * 264];
  const int m0 = blockIdx.x * 64, tid = threadIdx.x;
  const int c4 = tid & 63;
#pragma unroll
  for (int i = 0; i < 16; ++i) {
    int row = (tid >> 6) + i * 4;
    float4 f = ((const float4*)k)[(size_t)(m0 + row) * 64 + c4];
    uint32_t lo = f2bf(f.x) | ((uint32_t)f2bf(f.y) << 16);
    uint32_t hi = f2bf(f.z) | ((uint32_t)f2bf(f.w) << 16);
    *(uint2*)&lds[row * 264 + c4 * 4] = make_uint2(lo, hi);
  }
  __syncthreads();
  const int m = (tid >> 1) & 63, h = tid & 1, thi = tid >> 7;
#pragma unroll
  for (int tt = 0; tt < 8; ++tt) {
    int t = tt * 2 + thi;
    uint4 v = *(const uint4*)&lds[m * 264 + t * 16 + h * 8];
    ((uint4*)kp)[(size_t)(t * 8192 + m0 + m) * 2 + h] = v;
  }
}

// ---- prep: V [8192][256] f32 -> Vp fragment order ---------------------------
// Vp chunk (16B) index = (t*256 + n)*2 + h, holds V[t*16 + h*8 + j][n] bf16
__global__ __launch_bounds__(256) void pack_v(const float* __restrict__ v,
                                              unsigned short* __restrict__ vp) {
  __shared__ unsigned short lds[16 * 264];
  const int t = blockIdx.x, tid = threadIdx.x;
  const int c4 = tid & 63;
#pragma unroll
  for (int i = 0; i < 4; ++i) {
    int row = (tid >> 6) + i * 4;
    float4 f = ((const float4*)v)[(size_t)(t * 16 + row) * 64 + c4];
    uint32_t lo = f2bf(f.x) | ((uint32_t)f2bf(f.y) << 16);
    uint32_t hi = f2bf(f.z) | ((uint32_t)f2bf(f.w) << 16);
    *(uint2*)&lds[row * 264 + c4 * 4] = make_uint2(lo, hi);
  }
  __syncthreads();
#pragma unroll
  for (int p = 0; p < 2; ++p) {
    int cc = tid + p * 256;
    int n = cc >> 1, h = cc & 1;
    uint32_t w[4];
#pragma unroll
    for (int jj = 0; jj < 4; ++jj) {
      unsigned short a = lds[(h * 8 + 2 * jj) * 264 + n];
      unsigned short b = lds[(h * 8 + 2 * jj + 1) * 264 + n];
      w[jj] = (uint32_t)a | ((uint32_t)b << 16);
    }
    ((uint4*)vp)[(size_t)(t * 256 + n) * 2 + h] = make_uint4(w[0], w[1], w[2], w[3]);
  }
}

// ---- main attention ---------------------------------------------------------
// grid 1024 = 128 qblks x 8 splits (split = bid&7 -> XCD-affine L2 slices).
// 256 thr / 4 waves: wave (qt=w>>1, dh=w&1) owns 32q x 128dv.
// K: global->LDS double-buffered (1 barrier/iter). V: direct from L2.
// LDS: Kbuf 2x32KB | S 2x8KB (shared by dh-twins, benign identical race) = 80KB
__global__ __launch_bounds__(256, 2) void attn(const unsigned short* __restrict__ qbm,
                                               const unsigned short* __restrict__ kpm,
                                               const unsigned short* __restrict__ vpm,
                                               float* __restrict__ opart,
                                               float* __restrict__ meff) {
  extern __shared__ char smem[];
  AS3 char* sm3 = (AS3 char*)smem;

  const int tid = threadIdx.x;
  const int w = tid >> 6, lane = tid & 63;
  const int ml = lane & 31, h = lane >> 5;
  const int qt = w >> 1, dh = w & 1;
  const int bid = blockIdx.x;
  const int split = bid & 7, qblk = bid >> 3;
  const int q0 = qblk * BM;

  const uint4* vp4 = (const uint4*)vpm;
  char* sp = smem + 65536 + qt * 8192;     // S scratch, shared by the dh-twins

  // Q fragments: 32 q-rows x 256 d
  bf16x8 qf[16];
  {
    const char* qrow = (const char*)qbm + (size_t)(q0 + qt * 32 + ml) * 512 + h * 16;
#pragma unroll
    for (int s = 0; s < 16; ++s)
      qf[s] = __builtin_bit_cast(bf16x8, *(const uint4*)(qrow + s * 32));
  }

  f32x16 oa[4];
#pragma unroll
  for (int nt = 0; nt < 4; ++nt)
#pragma unroll
    for (int r = 0; r < 16; ++r) oa[nt][r] = 0.f;
  float m_run = -1e30f, l_run = 0.f;

  // stage K tile for iter 0 into buf0
  {
    const int kb = split * KPS;
#pragma unroll
    for (int i = 0; i < 8; ++i) {
      int s = i * 2 + (w >> 1), sub = (w & 1) * 64;
      const AS1 char* g = (const AS1 char*)kpm +
          ((size_t)s * 16384 + (size_t)kb * 2 + sub + lane) * 16;
      __builtin_amdgcn_global_load_lds((const AS1 uint32_t*)g,
          (AS3 uint32_t*)(sm3 + (i * 256 + w * 64) * 16), 16, 0, 0);
    }
  }

  for (int it = 0; it < ITERS; ++it) {
    const int kb = split * KPS + it * BN;
    const int t0 = kb >> 4;
    const char* kbuf = smem + (it & 1) * 32768;

    __syncthreads();     // stage(it) complete; buf[(it+1)&1] free to overwrite

    if (it + 1 < ITERS) {
      const int kb2 = kb + BN;
      AS3 char* dst = sm3 + ((it + 1) & 1) * 32768;
#pragma unroll
      for (int i = 0; i < 8; ++i) {
        int s = i * 2 + (w >> 1), sub = (w & 1) * 64;
        const AS1 char* g = (const AS1 char*)kpm +
            ((size_t)s * 16384 + (size_t)kb2 * 2 + sub + lane) * 16;
        __builtin_amdgcn_global_load_lds((const AS1 uint32_t*)g,
            (AS3 uint32_t*)(dst + (i * 256 + w * 64) * 16), 16, 0, 0);
      }
    }

    // ---- QK^T: S(32q x 64k), A = Q regs, B = K from LDS ----
    f32x16 sa0, sa1;
#pragma unroll
    for (int r = 0; r < 16; ++r) { sa0[r] = 0.f; sa1[r] = 0.f; }
#pragma unroll
    for (int s = 0; s < 16; ++s) {
      const char* base = kbuf + s * 2048 + h * 16;
      bf16x8 k0 = __builtin_bit_cast(bf16x8, *(const uint4*)(base + ml * 32));
      bf16x8 k1 = __builtin_bit_cast(bf16x8, *(const uint4*)(base + (32 + ml) * 32));
      sa0 = __builtin_amdgcn_mfma_f32_32x32x16_bf16(qf[s], k0, sa0, 0, 0, 0);
      sa1 = __builtin_amdgcn_mfma_f32_32x32x16_bf16(qf[s], k1, sa1, 0, 0, 0);
    }

    // ---- S -> LDS (XOR swizzle; twins write identical values) ----
#pragma unroll
    for (int r = 0; r < 16; ++r) {
      int row = (r & 3) + 8 * (r >> 2) + 4 * h;
      char* base = sp + row * 256;
      int rx = row & 15;
      *(float*)(base + (((ml >> 2) ^ rx) << 4) + (ml & 3) * 4) = sa0[r];
      *(float*)(base + ((((32 + ml) >> 2) ^ rx) << 4) + (ml & 3) * 4) = sa1[r];
    }

    // ---- online softmax: lane owns q-row = ml, h-half of keys ----
    float vals[32];
    {
      const char* base2 = sp + ml * 256;
      const int rx2 = ml & 15;
#pragma unroll
      for (int s = 0; s < 4; ++s) {
        int c0 = s * 4 + 2 * h;
        float4 a = *(const float4*)(base2 + ((c0 ^ rx2) << 4));
        float4 b = *(const float4*)(base2 + (((c0 + 1) ^ rx2) << 4));
        vals[s * 8 + 0] = a.x; vals[s * 8 + 1] = a.y; vals[s * 8 + 2] = a.z; vals[s * 8 + 3] = a.w;
        vals[s * 8 + 4] = b.x; vals[s * 8 + 5] = b.y; vals[s * 8 + 6] = b.z; vals[s * 8 + 7] = b.w;
      }
    }
    float mx = vals[0];
#pragma unroll
    for (int j = 1; j < 32; ++j) mx = fmaxf(mx, vals[j]);
    mx = fmaxf(mx, __shfl_xor(mx, 32));
    float mnew = fmaxf(m_run, mx);
    float al = __expf(m_run - mnew);
    float ls = 0.f;
#pragma unroll
    for (int j = 0; j < 32; ++j) { vals[j] = __expf(vals[j] - mnew); ls += vals[j]; }
    ls += __shfl_xor(ls, 32);
    l_run = l_run * al + ls;
    m_run = mnew;

    // ---- rescale O by alpha (alpha gathered by shuffle) ----
#pragma unroll
    for (int r = 0; r < 16; ++r) {
      float a = __shfl(al, (r & 3) + 8 * (r >> 2) + 4 * h);
#pragma unroll
      for (int nt = 0; nt < 4; ++nt) oa[nt][r] *= a;
    }

    // ---- P fragments (A-layout) straight from regs ----
    bf16x8 pf[4];
#pragma unroll
    for (int s = 0; s < 4; ++s) {
      uint32_t w0 = f2bf(vals[s * 8 + 0]) | ((uint32_t)f2bf(vals[s * 8 + 1]) << 16);
      uint32_t w1 = f2bf(vals[s * 8 + 2]) | ((uint32_t)f2bf(vals[s * 8 + 3]) << 16);
      uint32_t w2 = f2bf(vals[s * 8 + 4]) | ((uint32_t)f2bf(vals[s * 8 + 5]) << 16);
      uint32_t w3 = f2bf(vals[s * 8 + 6]) | ((uint32_t)f2bf(vals[s * 8 + 7]) << 16);
      pf[s] = __builtin_bit_cast(bf16x8, make_uint4(w0, w1, w2, w3));
    }

    // ---- PV: O(32q x 128dv) += P x V, B direct from L2 (s-outer for ILP) ----
#pragma unroll
    for (int s = 0; s < 4; ++s) {
#pragma unroll
      for (int nt = 0; nt < 4; ++nt) {
        bf16x8 vb = __builtin_bit_cast(bf16x8,
            vp4[(size_t)((t0 + s) * 256 + dh * 128 + nt * 32 + ml) * 2 + h]);
        oa[nt] = __builtin_amdgcn_mfma_f32_32x32x16_bf16(pf[s], vb, oa[nt], 0, 0, 0);
      }
    }
  }

  // ---- epilogue ----
#pragma unroll
  for (int r = 0; r < 16; ++r) {
    int row = (r & 3) + 8 * (r >> 2) + 4 * h;
    float inv = 1.f / __shfl(l_run, row);
    size_t base = ((size_t)split * 8192 + q0 + qt * 32 + row) * 256 + dh * 128;
#pragma unroll
    for (int nt = 0; nt < 4; ++nt)
      opart[base + nt * 32 + ml] = oa[nt][r] * inv;
  }
  if (dh == 0 && h == 0)
    meff[split * 8192 + q0 + qt * 32 + ml] = m_run + __logf(l_run);
}

// ---- combine: log-sum-exp merge of the 8 splits -----------------------------
__global__ __launch_bounds__(256) void combine(const float* __restrict__ opart,
                                               const float* __restrict__ meff,
                                               float* __restrict__ out) {
  const int r = blockIdx.x, t = threadIdx.x;
  float me[SPLIT], M = -1e30f;
#pragma unroll
  for (int s = 0; s < SPLIT; ++s) { me[s] = meff[s * 8192 + r]; M = fmaxf(M, me[s]); }
  float wsum = 0.f, acc = 0.f;
#pragma unroll
  for (int s = 0; s < SPLIT; ++s) {
    float wgt = __expf(me[s] - M);
    wsum += wgt;
    acc += wgt * opart[((size_t)s * 8192 + r) * 256 + t];
  }
  out[(size_t)r * 256 + t] = acc / wsum;
}

extern "C" void kernel_launch(void* const* d_in, const int* in_sizes, int n_in,
                              void* d_out, int out_size, void* d_ws, size_t ws_size,
                              hipStream_t stream) {
  const float* q = (const float*)d_in[0];
  const float* k = (const float*)d_in[1];
  const float* v = (const float*)d_in[2];
  char* ws = (char*)d_ws;
  unsigned short* qb = (unsigned short*)(ws + OFF_QB);
  unsigned short* kp = (unsigned short*)(ws + OFF_KP);
  unsigned short* vp = (unsigned short*)(ws + OFF_VP);
  float* op = (float*)(ws + OFF_OP);
  float* me = (float*)(ws + OFF_ME);
  float* out = (float*)d_out;

  hipFuncSetAttribute((const void*)attn, hipFuncAttributeMaxDynamicSharedMemorySize,
                      81920);

  cvt_q<<<2048, 256, 0, stream>>>(q, qb);
  pack_k<<<128, 256, 0, stream>>>(k, kp);
  pack_v<<<512, 256, 0, stream>>>(v, vp);
  attn<<<1024, 256, 81920, stream>>>(qb, kp, vp, op, me);
  combine<<<8192, 256, 0, stream>>>(op, me, out);
}

// Round 4
// 255.692 us; speedup vs baseline: 1.5404x; 1.3772x over previous
//
#include <hip/hip_runtime.h>
#include <cstdint>

#define AS1 __attribute__((address_space(1)))
#define AS3 __attribute__((address_space(3)))

typedef __attribute__((ext_vector_type(8))) __bf16 bf16x8;
typedef __attribute__((ext_vector_type(16))) float f32x16;

static constexpr int SPLIT = 4;
static constexpr int BM = 64;              // queries per block
static constexpr int BN = 64;              // keys per iteration
static constexpr int KPS = 8192 / SPLIT;   // 2048 keys per split
static constexpr int ITERS = KPS / BN;     // 32

// workspace layout (bytes); total ~44.2 MB
static constexpr size_t OFF_QB = 0;               // bf16 [8192][256] Q * 1/16
static constexpr size_t OFF_KP = 4ull << 20;      // bf16 K in (s,h)-plane-major frag order
static constexpr size_t OFF_VP = 8ull << 20;      // bf16 packed V frags
static constexpr size_t OFF_OP = 12ull << 20;     // f32 [4][8192][256] per-split O
static constexpr size_t OFF_ME = 44ull << 20;     // f32 [4][8192] m + log(l)

__device__ __forceinline__ unsigned short f2bf(float f) {
  uint32_t b = __builtin_bit_cast(uint32_t, f);
  b += 0x7fffu + ((b >> 16) & 1u);   // RNE
  return (unsigned short)(b >> 16);
}

// ---- fused prep: cvt_q | pack_k | pack_v ------------------------------------
// Kp chunk (16B) index = (t*2 + h)*8192 + m   holds K[m][t*16 + h*8 .. +7]
// Vp chunk (16B) index = (t*256 + n)*2 + h    holds V[t*16 + h*8 + j][n]
__global__ __launch_bounds__(256) void prep(const float* __restrict__ q,
                                            const float* __restrict__ k,
                                            const float* __restrict__ v,
                                            unsigned short* __restrict__ qb,
                                            unsigned short* __restrict__ kp,
                                            unsigned short* __restrict__ vp) {
  __shared__ unsigned short lds[64 * 264];
  const int bid = blockIdx.x, tid = threadIdx.x;
  if (bid < 2048) {                                  // ---- Q cast + scale ----
    int i = bid * 256 + tid;
    float4 f = ((const float4*)q)[i];
    ushort4 u;
    u.x = f2bf(f.x * 0.0625f); u.y = f2bf(f.y * 0.0625f);
    u.z = f2bf(f.z * 0.0625f); u.w = f2bf(f.w * 0.0625f);
    ((ushort4*)qb)[i] = u;
  } else if (bid < 2176) {                           // ---- pack K ----
    const int m0 = (bid - 2048) * 64;
    const int c4 = tid & 63;
#pragma unroll
    for (int i = 0; i < 16; ++i) {
      int row = (tid >> 6) + i * 4;
      float4 f = ((const float4*)k)[(size_t)(m0 + row) * 64 + c4];
      uint32_t lo = f2bf(f.x) | ((uint32_t)f2bf(f.y) << 16);
      uint32_t hi = f2bf(f.z) | ((uint32_t)f2bf(f.w) << 16);
      *(uint2*)&lds[row * 264 + c4 * 4] = make_uint2(lo, hi);
    }
    __syncthreads();
    const int m = tid & 63, hh = tid >> 7, t2 = (tid >> 6) & 1;
#pragma unroll
    for (int tt = 0; tt < 8; ++tt) {
      int t = tt * 2 + t2;
      uint4 w4 = *(const uint4*)&lds[m * 264 + t * 16 + hh * 8];
      ((uint4*)kp)[(size_t)(t * 2 + hh) * 8192 + m0 + m] = w4;
    }
  } else {                                           // ---- pack V ----
    const int t = bid - 2176;
    const int c4 = tid & 63;
#pragma unroll
    for (int i = 0; i < 4; ++i) {
      int row = (tid >> 6) + i * 4;
      float4 f = ((const float4*)v)[(size_t)(t * 16 + row) * 64 + c4];
      uint32_t lo = f2bf(f.x) | ((uint32_t)f2bf(f.y) << 16);
      uint32_t hi = f2bf(f.z) | ((uint32_t)f2bf(f.w) << 16);
      *(uint2*)&lds[row * 264 + c4 * 4] = make_uint2(lo, hi);
    }
    __syncthreads();
#pragma unroll
    for (int p = 0; p < 2; ++p) {
      int cc = tid + p * 256;
      int n = cc >> 1, h = cc & 1;
      uint32_t w4[4];
#pragma unroll
      for (int jj = 0; jj < 4; ++jj) {
        unsigned short a = lds[(h * 8 + 2 * jj) * 264 + n];
        unsigned short b = lds[(h * 8 + 2 * jj + 1) * 264 + n];
        w4[jj] = (uint32_t)a | ((uint32_t)b << 16);
      }
      ((uint4*)vp)[(size_t)(t * 256 + n) * 2 + h] = make_uint4(w4[0], w4[1], w4[2], w4[3]);
    }
  }
}

// ---- main attention ---------------------------------------------------------
// grid 512 = 128 qblks x 4 splits (split = bid&3; bid%8=XCD -> one split/XCD).
// 256 thr / 4 waves: wave (qt=w>>1, dh=w&1) owns 32q x 128dv (QK duplicated
// across dh twins -> wave-private softmax, 1 barrier/iter).
// K: global->LDS dbuf via global_load_lds, (s,h)-plane-major => conflict-free
// ds_read_b128. V: direct from L2 (parallel port). LDS = 64K K + 16K S = 80KB
// -> exactly 2 blocks/CU.
__global__ __launch_bounds__(256, 2) void attn(const unsigned short* __restrict__ qbm,
                                               const unsigned short* __restrict__ kpm,
                                               const unsigned short* __restrict__ vpm,
                                               float* __restrict__ opart,
                                               float* __restrict__ meff) {
  extern __shared__ char smem[];
  AS3 char* sm3 = (AS3 char*)smem;

  const int tid = threadIdx.x;
  const int w = tid >> 6, lane = tid & 63;
  const int ml = lane & 31, h = lane >> 5;
  const int qt = w >> 1, dh = w & 1;
  const int bid = blockIdx.x;
  const int split = bid & 3, qblk = bid >> 2;
  const int q0 = qblk * BM;

  const uint4* vp4 = (const uint4*)vpm;
  char* sp = smem + 65536 + qt * 8192;     // S scratch, shared by dh-twins

  // Q fragments: 32 q-rows x 256 d
  bf16x8 qf[16];
  {
    const char* qrow = (const char*)qbm + (size_t)(q0 + qt * 32 + ml) * 512 + h * 16;
#pragma unroll
    for (int s = 0; s < 16; ++s)
      qf[s] = __builtin_bit_cast(bf16x8, *(const uint4*)(qrow + s * 32));
  }

  f32x16 oa[4];
#pragma unroll
  for (int nt = 0; nt < 4; ++nt)
#pragma unroll
    for (int r = 0; r < 16; ++r) oa[nt][r] = 0.f;
  float m_run = -1e30f, l_run = 0.f;

  // stage K tile for iter 0 into buf0: 32 planes x 64 chunks x 16B
  {
    const int kb = split * KPS;
#pragma unroll
    for (int i = 0; i < 8; ++i) {
      int p = i * 4 + w;
      const AS1 char* g = (const AS1 char*)kpm + ((size_t)p * 8192 + kb + lane) * 16;
      __builtin_amdgcn_global_load_lds((const AS1 uint32_t*)g,
          (AS3 uint32_t*)(sm3 + p * 1024 + lane * 16), 16, 0, 0);
    }
  }

  for (int it = 0; it < ITERS; ++it) {
    const int kb = split * KPS + it * BN;
    const int t0 = kb >> 4;
    const char* kbuf = smem + (it & 1) * 32768;

    __syncthreads();     // stage(it) complete; buf[(it+1)&1] free to overwrite

    if (it + 1 < ITERS) {
      const int kb2 = kb + BN;
      AS3 char* dst = sm3 + ((it + 1) & 1) * 32768;
#pragma unroll
      for (int i = 0; i < 8; ++i) {
        int p = i * 4 + w;
        const AS1 char* g = (const AS1 char*)kpm + ((size_t)p * 8192 + kb2 + lane) * 16;
        __builtin_amdgcn_global_load_lds((const AS1 uint32_t*)g,
            (AS3 uint32_t*)(dst + p * 1024 + lane * 16), 16, 0, 0);
      }
    }

    // ---- QK^T: S(32q x 64k), A = Q regs, B = K LDS (contiguous b128) ----
    f32x16 sa0, sa1;
#pragma unroll
    for (int r = 0; r < 16; ++r) { sa0[r] = 0.f; sa1[r] = 0.f; }
#pragma unroll
    for (int s = 0; s < 16; ++s) {
      const char* b0 = kbuf + s * 2048 + h * 1024;
      bf16x8 k0 = __builtin_bit_cast(bf16x8, *(const uint4*)(b0 + ml * 16));
      bf16x8 k1 = __builtin_bit_cast(bf16x8, *(const uint4*)(b0 + 512 + ml * 16));
      sa0 = __builtin_amdgcn_mfma_f32_32x32x16_bf16(qf[s], k0, sa0, 0, 0, 0);
      sa1 = __builtin_amdgcn_mfma_f32_32x32x16_bf16(qf[s], k1, sa1, 0, 0, 0);
    }

    // ---- wave-shared tile max (any ref >= row max is exact for online sm) ----
    float M = sa0[0];
#pragma unroll
    for (int r = 0; r < 16; ++r) { M = fmaxf(M, sa0[r]); M = fmaxf(M, sa1[r]); }
#pragma unroll
    for (int d = 1; d < 64; d <<= 1) M = fmaxf(M, __shfl_xor(M, d));
    const float mnew = fmaxf(m_run, M);
    const float al = __expf(m_run - mnew);
    m_run = mnew;

    // ---- S -> LDS (XOR swizzle; twins write identical values) ----
#pragma unroll
    for (int r = 0; r < 16; ++r) {
      int row = (r & 3) + 8 * (r >> 2) + 4 * h;
      char* base = sp + row * 256;
      int rx = row & 15;
      *(float*)(base + (((ml >> 2) ^ rx) << 4) + (ml & 3) * 4) = sa0[r];
      *(float*)(base + ((((32 + ml) >> 2) ^ rx) << 4) + (ml & 3) * 4) = sa1[r];
    }

    // ---- read + exp + pack P frags (lane = row ml, its A-frag k-range) ----
    bf16x8 pf[4];
    float ls = 0.f;
    {
      const char* base2 = sp + ml * 256;
      const int rx2 = ml & 15;
#pragma unroll
      for (int s = 0; s < 4; ++s) {
        int c0 = s * 4 + 2 * h;
        float4 a = *(const float4*)(base2 + ((c0 ^ rx2) << 4));
        float4 b = *(const float4*)(base2 + (((c0 + 1) ^ rx2) << 4));
        float e0 = __expf(a.x - mnew), e1 = __expf(a.y - mnew);
        float e2 = __expf(a.z - mnew), e3 = __expf(a.w - mnew);
        float e4 = __expf(b.x - mnew), e5 = __expf(b.y - mnew);
        float e6 = __expf(b.z - mnew), e7 = __expf(b.w - mnew);
        ls += (e0 + e1 + e2 + e3) + (e4 + e5 + e6 + e7);
        uint32_t w0 = f2bf(e0) | ((uint32_t)f2bf(e1) << 16);
        uint32_t w1 = f2bf(e2) | ((uint32_t)f2bf(e3) << 16);
        uint32_t w2 = f2bf(e4) | ((uint32_t)f2bf(e5) << 16);
        uint32_t w3 = f2bf(e6) | ((uint32_t)f2bf(e7) << 16);
        pf[s] = __builtin_bit_cast(bf16x8, make_uint4(w0, w1, w2, w3));
      }
    }
    ls += __shfl_xor(ls, 32);
    l_run = l_run * al + ls;

    // ---- rescale O by scalar alpha ----
#pragma unroll
    for (int nt = 0; nt < 4; ++nt)
#pragma unroll
      for (int r = 0; r < 16; ++r) oa[nt][r] *= al;

    // ---- PV: O(32q x 128dv) += P x V, B direct from L2 ----
#pragma unroll
    for (int s = 0; s < 4; ++s) {
#pragma unroll
      for (int nt = 0; nt < 4; ++nt) {
        bf16x8 vb = __builtin_bit_cast(bf16x8,
            vp4[(size_t)((t0 + s) * 256 + dh * 128 + nt * 32 + ml) * 2 + h]);
        oa[nt] = __builtin_amdgcn_mfma_f32_32x32x16_bf16(pf[s], vb, oa[nt], 0, 0, 0);
      }
    }
  }

  // ---- epilogue ----
#pragma unroll
  for (int r = 0; r < 16; ++r) {
    int row = (r & 3) + 8 * (r >> 2) + 4 * h;
    float inv = 1.f / __shfl(l_run, row);
    size_t base = ((size_t)split * 8192 + q0 + qt * 32 + row) * 256 + dh * 128;
#pragma unroll
    for (int nt = 0; nt < 4; ++nt)
      opart[base + nt * 32 + ml] = oa[nt][r] * inv;
  }
  if (dh == 0 && h == 0)
    meff[split * 8192 + q0 + qt * 32 + ml] = m_run + __logf(l_run);
}

// ---- combine: log-sum-exp merge of the 4 splits -----------------------------
__global__ __launch_bounds__(256) void combine(const float* __restrict__ opart,
                                               const float* __restrict__ meff,
                                               float* __restrict__ out) {
  const int r = blockIdx.x, t = threadIdx.x;
  float me[SPLIT], M = -1e30f;
#pragma unroll
  for (int s = 0; s < SPLIT; ++s) { me[s] = meff[s * 8192 + r]; M = fmaxf(M, me[s]); }
  float wsum = 0.f, acc = 0.f;
#pragma unroll
  for (int s = 0; s < SPLIT; ++s) {
    float wgt = __expf(me[s] - M);
    wsum += wgt;
    acc += wgt * opart[((size_t)s * 8192 + r) * 256 + t];
  }
  out[(size_t)r * 256 + t] = acc / wsum;
}

extern "C" void kernel_launch(void* const* d_in, const int* in_sizes, int n_in,
                              void* d_out, int out_size, void* d_ws, size_t ws_size,
                              hipStream_t stream) {
  const float* q = (const float*)d_in[0];
  const float* k = (const float*)d_in[1];
  const float* v = (const float*)d_in[2];
  char* ws = (char*)d_ws;
  unsigned short* qb = (unsigned short*)(ws + OFF_QB);
  unsigned short* kp = (unsigned short*)(ws + OFF_KP);
  unsigned short* vp = (unsigned short*)(ws + OFF_VP);
  float* op = (float*)(ws + OFF_OP);
  float* me = (float*)(ws + OFF_ME);
  float* out = (float*)d_out;

  hipFuncSetAttribute((const void*)attn, hipFuncAttributeMaxDynamicSharedMemorySize,
                      81920);

  prep<<<2688, 256, 0, stream>>>(q, k, v, qb, kp, vp);
  attn<<<512, 256, 81920, stream>>>(qb, kp, vp, op, me);
  combine<<<8192, 256, 0, stream>>>(op, me, out);
}